// Round 6
// baseline (1179.832 us; speedup 1.0000x reference)
//
#include <hip/hip_runtime.h>
#include <hip/hip_cooperative_groups.h>
#include <stdint.h>

namespace cg = cooperative_groups;

// Top-k (k=10% of N) by value over flat fp32; scatter values back, zeros
// elsewhere. SINGLE cooperative dispatch (R5 lesson: ~20us per dispatch gap;
// 10 dispatches = 200us of pure overhead).
// Phases (grid.sync between):
//  P0 all:    zero ws metadata + fine hist; gather 16K coalesced samples
//  P1 blk0:   two-level sample scan -> 2^21-code window center estimate
//  P2 all:    full read pass: count u>window (registers only) + per-code
//             global hist (+chunk csum) inside the window (~1.5M spread
//             atomics; NO per-element LDS atomics - R5 lesson)
//  P3 blk0:   exact threshold t_u + tie count from csum+fine, or !OK flag
//  P4 all:    (!OK only, ~never: exact 16+16-bit radix fallback in-kernel)
//             scatter: out = (u>t_u) ? x : 0; collect ==t_u indices
//  P5 blk0:   stable tie-break (smallest indices win, matching lax.top_k)
// Lessons: R2 no same-address returning-atomic bursts; R3 no strided
// sampling; R4 ~20us/dispatch; R5 no concentrated LDS-atomic histograms.

#define EQ_CAP 65536
#define NSAMP 16384

#define SC_WLO   0
#define SC_ABOVE 1
#define SC_TU    2
#define SC_NEED  3
#define SC_EQN   4
#define SC_OK    5
#define SC_FBHI  6
#define SC_FBKR  7

__device__ __forceinline__ unsigned int f2u(float x) {
    unsigned int b = __float_as_uint(x);
    return (b & 0x80000000u) ? ~b : (b | 0x80000000u);
}
__device__ __forceinline__ float u2f(unsigned int u) {
    return __uint_as_float((u & 0x80000000u) ? (u & 0x7FFFFFFFu) : ~u);
}
__device__ __forceinline__ unsigned int vload(const unsigned int* p) {
    return *(volatile const unsigned int*)p;
}

__device__ __forceinline__ unsigned int block_exscan256(unsigned int v,
                                                        unsigned int* lds,
                                                        int tid)
{
    lds[tid] = v;
    __syncthreads();
    for (int off = 1; off < 256; off <<= 1) {
        unsigned int t = (tid >= off) ? lds[tid - off] : 0u;
        __syncthreads();
        lds[tid] += t;
        __syncthreads();
    }
    return lds[tid] - v;
}

// block0: descending scan of a 65536-bin global hist (two-pass, L2 reads)
__device__ void scan64k_desc(const unsigned int* __restrict__ h,
                             unsigned int krem, unsigned int* lds, int tid,
                             unsigned int* outBin, unsigned int* outKr,
                             unsigned int* sc, int binSlot, int krSlot)
{
    unsigned int part = 0u;
    for (int j = 0; j < 256; ++j) part += h[65535 - (tid * 256 + j)];
    unsigned int ex = block_exscan256(part, lds, tid);
    unsigned int cum = ex;
    for (int j = 0; j < 256; ++j) {
        int bin = 65535 - (tid * 256 + j);
        unsigned int c = h[bin];
        if (cum < krem && cum + c >= krem) {
            sc[binSlot] = (unsigned int)bin;
            sc[krSlot]  = krem - cum;
        }
        cum += c;
    }
}

__global__ void __launch_bounds__(256, 4)
topk_coop(const float* __restrict__ x, float* __restrict__ out,
          int n4, long long N,
          unsigned int* __restrict__ sc, unsigned int* __restrict__ csum,
          unsigned int* __restrict__ eq_list, unsigned int* __restrict__ samp,
          unsigned int* __restrict__ fine,
          unsigned int* __restrict__ fbA, unsigned int* __restrict__ fbB,
          unsigned int k, unsigned int ks, unsigned int wbits)
{
    cg::grid_group grid = cg::this_grid();
    __shared__ unsigned int lh[2048];
    __shared__ unsigned int lds[256];
    __shared__ unsigned int shv[4];
    const int tid = threadIdx.x;
    const int bid = blockIdx.x;
    const int nth = gridDim.x * 256;
    const int g = bid * 256 + tid;
    const unsigned int wsize = 1u << wbits;
    const int nc = 1 << (wbits - 10);          // csum chunks (<=2048)
    const float4* x4 = (const float4*)x;
    float4* o4 = (float4*)out;
    const long long t0 = (long long)n4 * 4;
    const int tail = (int)(N - t0);

    // ---------------- P0: zero + sample ----------------
    if (g < 64) sc[g] = 0u;
    for (int i = g; i < nc; i += nth) csum[i] = 0u;
    for (unsigned int i = g; i < wsize; i += nth) fine[i] = 0u;
    {
        long long cstride = N >> 10; if (cstride < 16) cstride = 16;
        for (int i = g; i < NSAMP; i += nth) {
            long long idx = (long long)(i >> 4) * cstride + (i & 15);
            if (idx >= N) idx = N - 1;
            samp[i] = f2u(x[idx]);
        }
    }
    grid.sync();

    // ---------------- P1: block0 two-level sample scan ----------------
    if (bid == 0) {
        for (int i = tid; i < 2048; i += 256) lh[i] = 0u;
        __syncthreads();
        for (int i = tid; i < NSAMP; i += 256) atomicAdd(&lh[samp[i] >> 21], 1u);
        __syncthreads();
        unsigned int loc[8], part = 0u;
        for (int j = 0; j < 8; ++j) { unsigned int v = lh[2047 - (tid * 8 + j)]; loc[j] = v; part += v; }
        unsigned int ex = block_exscan256(part, lds, tid);
        unsigned int cum = ex;
        for (int j = 0; j < 8; ++j) {
            int bin = 2047 - (tid * 8 + j); unsigned int c = loc[j];
            if (cum < ks && cum + c >= ks) { shv[0] = (unsigned int)bin; shv[1] = ks - cum; }
            cum += c;
        }
        __syncthreads();
        unsigned int B = shv[0], kr = shv[1];
        for (int i = tid; i < 2048; i += 256) lh[i] = 0u;
        __syncthreads();
        for (int i = tid; i < NSAMP; i += 256) {
            unsigned int u = samp[i];
            if ((u >> 21) == B) atomicAdd(&lh[(u >> 10) & 2047u], 1u);
        }
        __syncthreads();
        part = 0u;
        for (int j = 0; j < 8; ++j) { unsigned int v = lh[2047 - (tid * 8 + j)]; loc[j] = v; part += v; }
        ex = block_exscan256(part, lds, tid);
        cum = ex;
        for (int j = 0; j < 8; ++j) {
            int bin = 2047 - (tid * 8 + j); unsigned int c = loc[j];
            if (cum < kr && cum + c >= kr) {
                unsigned int uhat = (B << 21) | ((unsigned int)bin << 10) | 512u;
                unsigned int half = wsize >> 1;
                unsigned int wlo = (uhat > half) ? (uhat - half) : 0u;
                unsigned int wlomax = 0u - wsize;
                if (wlo > wlomax) wlo = wlomax;
                sc[SC_WLO] = wlo;
            }
            cum += c;
        }
        __threadfence();
    }
    grid.sync();

    // ---------------- P2: full selection pass ----------------
    {
        unsigned int wlo = vload(&sc[SC_WLO]);
        unsigned int whi = wlo + wsize - 1u;
        unsigned int above = 0u;
        for (int i = g; i < n4; i += nth) {
            float4 v = x4[i];
            unsigned int u;
            u = f2u(v.x); if (u > whi) ++above; else if (u >= wlo) { unsigned int o = u - wlo; atomicAdd(&fine[o], 1u); atomicAdd(&csum[o >> 10], 1u); }
            u = f2u(v.y); if (u > whi) ++above; else if (u >= wlo) { unsigned int o = u - wlo; atomicAdd(&fine[o], 1u); atomicAdd(&csum[o >> 10], 1u); }
            u = f2u(v.z); if (u > whi) ++above; else if (u >= wlo) { unsigned int o = u - wlo; atomicAdd(&fine[o], 1u); atomicAdd(&csum[o >> 10], 1u); }
            u = f2u(v.w); if (u > whi) ++above; else if (u >= wlo) { unsigned int o = u - wlo; atomicAdd(&fine[o], 1u); atomicAdd(&csum[o >> 10], 1u); }
        }
        if (bid == 0 && tid < tail) {
            unsigned int u = f2u(x[t0 + tid]);
            if (u > whi) ++above; else if (u >= wlo) { unsigned int o = u - wlo; atomicAdd(&fine[o], 1u); atomicAdd(&csum[o >> 10], 1u); }
        }
        for (int o = 32; o; o >>= 1) above += __shfl_down(above, o, 64);
        if ((tid & 63) == 0) shv[tid >> 6] = above;
        __syncthreads();
        if (tid == 0) {
            unsigned int s = shv[0] + shv[1] + shv[2] + shv[3];
            if (s) atomicAdd(&sc[SC_ABOVE], s);     // non-returning, 1/block
        }
    }
    grid.sync();

    // ---------------- P3: block0 exact threshold ----------------
    if (bid == 0) {
        unsigned int above = vload(&sc[SC_ABOVE]);
        int seg = nc >> 8;
        unsigned int loc[8], part = 0u;
        for (int j = 0; j < seg; ++j) { unsigned int v = csum[nc - 1 - (tid * seg + j)]; loc[j] = v; part += v; }
        unsigned int ex = block_exscan256(part, lds, tid);
        if (tid == 255) shv[3] = ex + part;
        __syncthreads();
        unsigned int total = shv[3];
        unsigned int valid = (above < k) && ((k - above) <= total);
        if (tid == 0) sc[SC_OK] = valid;
        if (valid) {
            unsigned int krem = k - above;
            unsigned int cum = ex;
            for (int j = 0; j < seg; ++j) {
                int c = nc - 1 - (tid * seg + j); unsigned int cc = loc[j];
                if (cum < krem && cum + cc >= krem) { shv[0] = (unsigned int)c; shv[1] = krem - cum; }
                cum += cc;
            }
            __syncthreads();
            unsigned int C = shv[0], kr2 = shv[1];
            unsigned int l3[4], p3 = 0u;
            for (int j = 0; j < 4; ++j) { unsigned int v = fine[C * 1024u + (1023u - (tid * 4 + j))]; l3[j] = v; p3 += v; }
            __syncthreads();
            unsigned int e3 = block_exscan256(p3, lds, tid);
            unsigned int cum3 = e3;
            for (int j = 0; j < 4; ++j) {
                unsigned int bin = 1023u - (tid * 4 + j); unsigned int cc = l3[j];
                if (cum3 < kr2 && cum3 + cc >= kr2) {
                    sc[SC_TU] = vload(&sc[SC_WLO]) + C * 1024u + bin;
                    sc[SC_NEED] = kr2 - cum3;
                }
                cum3 += cc;
            }
        }
        __threadfence();
    }
    grid.sync();

    // ---------------- P4: (fallback) + scatter ----------------
    {
        unsigned int ok = vload(&sc[SC_OK]);   // grid-uniform
        if (!ok) {
            // exact 16+16 radix fallback (window missed; ~never taken)
            for (int i = g; i < 65536; i += nth) { fbA[i] = 0u; fbB[i] = 0u; }
            grid.sync();
            for (int i = g; i < n4; i += nth) {
                float4 v = x4[i];
                atomicAdd(&fbA[f2u(v.x) >> 16], 1u);
                atomicAdd(&fbA[f2u(v.y) >> 16], 1u);
                atomicAdd(&fbA[f2u(v.z) >> 16], 1u);
                atomicAdd(&fbA[f2u(v.w) >> 16], 1u);
            }
            if (bid == 0 && tid < tail) atomicAdd(&fbA[f2u(x[t0 + tid]) >> 16], 1u);
            grid.sync();
            if (bid == 0) {
                scan64k_desc(fbA, k, lds, tid, 0, 0, sc, SC_FBHI, SC_FBKR);
                __threadfence();
            }
            grid.sync();
            unsigned int pref = vload(&sc[SC_FBHI]);
            for (int i = g; i < n4; i += nth) {
                float4 v = x4[i];
                unsigned int u;
                u = f2u(v.x); if ((u >> 16) == pref) atomicAdd(&fbB[u & 0xFFFFu], 1u);
                u = f2u(v.y); if ((u >> 16) == pref) atomicAdd(&fbB[u & 0xFFFFu], 1u);
                u = f2u(v.z); if ((u >> 16) == pref) atomicAdd(&fbB[u & 0xFFFFu], 1u);
                u = f2u(v.w); if ((u >> 16) == pref) atomicAdd(&fbB[u & 0xFFFFu], 1u);
            }
            if (bid == 0 && tid < tail) {
                unsigned int u = f2u(x[t0 + tid]);
                if ((u >> 16) == pref) atomicAdd(&fbB[u & 0xFFFFu], 1u);
            }
            grid.sync();
            if (bid == 0) {
                unsigned int kr = vload(&sc[SC_FBKR]);
                scan64k_desc(fbB, kr, lds, tid, 0, 0, sc, SC_TU, SC_NEED);
                if (tid == 0) sc[SC_TU] |= (pref << 16);
                __threadfence();
            }
            grid.sync();
        }
        unsigned int tu = vload(&sc[SC_TU]);
        for (int i = g; i < n4; i += nth) {
            float4 v = x4[i];
            unsigned int u0 = f2u(v.x), u1 = f2u(v.y), u2 = f2u(v.z), u3 = f2u(v.w);
            float4 o;
            o.x = (u0 > tu) ? v.x : 0.0f;
            o.y = (u1 > tu) ? v.y : 0.0f;
            o.z = (u2 > tu) ? v.z : 0.0f;
            o.w = (u3 > tu) ? v.w : 0.0f;
            if (u0 == tu || u1 == tu || u2 == tu || u3 == tu) {   // ~handful/launch
                unsigned int b = (unsigned int)i * 4u;
                if (u0 == tu) { unsigned int p = atomicAdd(&sc[SC_EQN], 1u); if (p < (unsigned int)EQ_CAP) eq_list[p] = b + 0u; }
                if (u1 == tu) { unsigned int p = atomicAdd(&sc[SC_EQN], 1u); if (p < (unsigned int)EQ_CAP) eq_list[p] = b + 1u; }
                if (u2 == tu) { unsigned int p = atomicAdd(&sc[SC_EQN], 1u); if (p < (unsigned int)EQ_CAP) eq_list[p] = b + 2u; }
                if (u3 == tu) { unsigned int p = atomicAdd(&sc[SC_EQN], 1u); if (p < (unsigned int)EQ_CAP) eq_list[p] = b + 3u; }
            }
            o4[i] = o;
        }
        if (bid == 0 && tid < tail) {
            long long idx = t0 + tid;
            float v = x[idx]; unsigned int u = f2u(v);
            out[idx] = (u > tu) ? v : 0.0f;
            if (u == tu) { unsigned int p = atomicAdd(&sc[SC_EQN], 1u); if (p < (unsigned int)EQ_CAP) eq_list[p] = (unsigned int)idx; }
        }
    }
    grid.sync();

    // ---------------- P5: block0 stable tie-fix ----------------
    if (bid == 0) {
        unsigned int m = vload(&sc[SC_EQN]); if (m > (unsigned int)EQ_CAP) m = EQ_CAP;
        unsigned int need = vload(&sc[SC_NEED]);
        float f = u2f(vload(&sc[SC_TU]));
        for (unsigned int j = tid; j < m; j += 256u) {
            unsigned int idx = eq_list[j]; unsigned int c = 0u;
            for (unsigned int l = 0; l < m; ++l) c += (eq_list[l] < idx) ? 1u : 0u;
            if (c < need) out[idx] = f;
        }
    }
}

extern "C" void kernel_launch(void* const* d_in, const int* in_sizes, int n_in,
                              void* d_out, int out_size, void* d_ws, size_t ws_size,
                              hipStream_t stream) {
    const float* x = (const float*)d_in[0];
    float* out = (float*)d_out;
    long long N = (long long)in_sizes[0];
    int n4 = (int)(N >> 2);
    unsigned int k = (unsigned int)((double)N * 0.1);
    if (k == 0u) k = 1u;
    unsigned int ks = (unsigned int)((double)NSAMP * (double)k / (double)N);
    if (ks < 1u) ks = 1u; if (ks > (unsigned int)NSAMP) ks = NSAMP;

    unsigned int wbits = 21;
    if (ws_size < ((size_t)2 << 20) + ((size_t)4u << 21)) wbits = 19;

    // ws: sc@0(256B) csum@1K(8KB) eq@32K(256KB) samp@294912(64KB)
    //     fbA@360448(256KB) fbB@622592(256KB) fine@2M(8MB for wbits=21)
    uint8_t* w = (uint8_t*)d_ws;
    unsigned int* sc      = (unsigned int*)w;
    unsigned int* csum    = (unsigned int*)(w + 1024);
    unsigned int* eq_list = (unsigned int*)(w + 32768);
    unsigned int* samp    = (unsigned int*)(w + 294912);
    unsigned int* fbA     = (unsigned int*)(w + 360448);
    unsigned int* fbB     = (unsigned int*)(w + 622592);
    unsigned int* fine    = (unsigned int*)(w + ((size_t)2 << 20));

    int maxb = 0;
    hipError_t e = hipOccupancyMaxActiveBlocksPerMultiprocessor(
        &maxb, (const void*)topk_coop, 256, 0);
    if (e != hipSuccess || maxb < 1) maxb = 1;
    if (maxb > 8) maxb = 8;
    int grid = 256 * maxb;               // MI355X: 256 CUs
    if (grid > 2048) grid = 2048;

    void* args[] = { (void*)&x, (void*)&out, (void*)&n4, (void*)&N,
                     (void*)&sc, (void*)&csum, (void*)&eq_list, (void*)&samp,
                     (void*)&fine, (void*)&fbA, (void*)&fbB,
                     (void*)&k, (void*)&ks, (void*)&wbits };
    hipLaunchCooperativeKernel((const void*)topk_coop, dim3(grid), dim3(256),
                               args, 0, stream);
}